// Round 7
// baseline (133.669 us; speedup 1.0000x reference)
//
#include <hip/hip_runtime.h>

typedef unsigned short u16;
typedef short bf16x8 __attribute__((ext_vector_type(8)));
typedef float f32x4 __attribute__((ext_vector_type(4)));

#define BB 8
#define CC 768
#define NN 256
#define HH 12
#define DD 64
#define K3 3072          // H*N
#define BCN 196608       // C*N per batch
#define SCALE 0.125f
#define LDP 72           // LDS pitch (u16): 144B rows, 16B-aligned, 2-way banks only

__device__ __forceinline__ u16 f2b(float f) {
    union { float f; unsigned int i; } v; v.f = f;
    unsigned int r = v.i + 0x7FFFu + ((v.i >> 16) & 1u);
    return (u16)(r >> 16);
}

// one 64x64x64 MFMA macro-step (4 waves, each 32x32, K=64 in two k-halves)
#define MFMA8(ASP, BSP, ACC)                                                              \
    _Pragma("unroll")                                                                     \
    for (int kk = 0; kk < 2; ++kk) {                                                      \
        bf16x8 a0 = *reinterpret_cast<bf16x8*>((ASP) + (wm + tx) * LDP + kk * 32 + q * 8);\
        bf16x8 a1 = *reinterpret_cast<bf16x8*>((ASP) + (wm + 16 + tx) * LDP + kk * 32 + q * 8);\
        bf16x8 b0 = *reinterpret_cast<bf16x8*>((BSP) + (wn + tx) * LDP + kk * 32 + q * 8);\
        bf16x8 b1 = *reinterpret_cast<bf16x8*>((BSP) + (wn + 16 + tx) * LDP + kk * 32 + q * 8);\
        ACC[0][0] = __builtin_amdgcn_mfma_f32_16x16x32_bf16(a0, b0, ACC[0][0], 0, 0, 0);  \
        ACC[0][1] = __builtin_amdgcn_mfma_f32_16x16x32_bf16(a0, b1, ACC[0][1], 0, 0, 0);  \
        ACC[1][0] = __builtin_amdgcn_mfma_f32_16x16x32_bf16(a1, b0, ACC[1][0], 0, 0, 0);  \
        ACC[1][1] = __builtin_amdgcn_mfma_f32_16x16x32_bf16(a1, b1, ACC[1][1], 0, 0, 0);  \
    }

// ---------------------------------------------------------------------------
// Stage 1: cp[b,o,n] = sum_c Wp[o,c]*cross[b,c,n] + bp[o]     (bf16 out)
// R4-proven version (1-deep register prefetch, single-buffer, 3 barriers/iter).
// Blocks (0,0,b) zero G[b] AND the k_gx counters (stream-ordered handoff).
// ---------------------------------------------------------------------------
__global__ __launch_bounds__(256) void k_proj(
    const float* __restrict__ Wp, const float* __restrict__ cross,
    const float* __restrict__ bp, u16* __restrict__ cp, float* __restrict__ G,
    unsigned int* __restrict__ Cnt)
{
    __shared__ __align__(16) u16 As[64 * LDP];
    __shared__ __align__(16) u16 Bs[64 * LDP];
    __shared__ __align__(16) float T[64][68];
    const int n0 = blockIdx.x * 64;
    const int o0 = blockIdx.y * 64;
    const int b  = blockIdx.z;
    const int t = threadIdx.x;
    const int lane = t & 63, wave = t >> 6;
    const int q = lane >> 4, tx = lane & 15;
    const int wm = (wave & 1) * 32, wn = (wave >> 1) * 32;
    const int r4 = t >> 2, cq = t & 3;

    if (blockIdx.x == 0 && blockIdx.y == 0) {   // zero G[b] + counter[b]
        float4 z = {0.f, 0.f, 0.f, 0.f};
        float* Gb = G + b * 4096;
        #pragma unroll
        for (int j = 0; j < 4; ++j)
            *reinterpret_cast<float4*>(Gb + t * 4 + j * 1024) = z;
        if (t == 0) Cnt[b] = 0u;
    }

    const float* crb = cross + b * BCN;
    const float* wsrc = Wp + (o0 + r4) * CC;    // contiguous row o0+r4

    f32x4 acc[2][2] = {};
    float4 ra[4], rc[4];
    #pragma unroll
    for (int u = 0; u < 4; ++u) {               // prologue: iter-0 tiles -> regs
        const int cl = (cq + 4 * u) * 4;
        ra[u] = *reinterpret_cast<const float4*>(wsrc + cl);
        rc[u] = *reinterpret_cast<const float4*>(crb + r4 * NN + n0 + cl);
    }
    for (int it = 0; it < 12; ++it) {
        if (it > 0) __syncthreads();            // prev MFMA readers of As/Bs done
        {   // regs -> As (cvt) and T (f32)
            u16* dstA = As + r4 * LDP;
            #pragma unroll
            for (int u = 0; u < 4; ++u) {
                const int cl = (cq + 4 * u) * 4;
                ushort4 w; w.x = f2b(ra[u].x); w.y = f2b(ra[u].y);
                w.z = f2b(ra[u].z); w.w = f2b(ra[u].w);
                *reinterpret_cast<ushort4*>(dstA + cl) = w;
                T[r4][cl + 0] = rc[u].x; T[r4][cl + 1] = rc[u].y;
                T[r4][cl + 2] = rc[u].z; T[r4][cl + 3] = rc[u].w;
            }
        }
        if (it < 11) {   // issue next-iter loads; in flight across transpose+MFMA
            const int c0 = (it + 1) * 64;
            #pragma unroll
            for (int u = 0; u < 4; ++u) {
                const int cl = (cq + 4 * u) * 4;
                ra[u] = *reinterpret_cast<const float4*>(wsrc + c0 + cl);
                rc[u] = *reinterpret_cast<const float4*>(crb + (c0 + r4) * NN + n0 + cl);
            }
        }
        __syncthreads();
        {   // Bs[n][c] = cvt(T[c][n])  (transpose; T col reads are 2-way = free)
            const int nn = t >> 2, dq = t & 3;
            u16* dst = Bs + nn * LDP;
            #pragma unroll
            for (int u = 0; u < 4; ++u) {
                const int c4 = (dq + 4 * u) * 4;
                ushort4 w;
                w.x = f2b(T[c4 + 0][nn]); w.y = f2b(T[c4 + 1][nn]);
                w.z = f2b(T[c4 + 2][nn]); w.w = f2b(T[c4 + 3][nn]);
                *reinterpret_cast<ushort4*>(dst + c4) = w;
            }
        }
        __syncthreads();
        MFMA8(As, Bs, acc)
    }
    u16* cpb = cp + b * BCN;
    #pragma unroll
    for (int i = 0; i < 2; ++i)
        #pragma unroll
        for (int j = 0; j < 2; ++j)
            #pragma unroll
            for (int r = 0; r < 4; ++r) {
                const int o = o0 + wm + i * 16 + q * 4 + r;
                const int n = n0 + wn + j * 16 + tx;
                cpb[o * NN + n] = f2b(acc[i][j][r] + bp[o]);
            }
}

// ---------------------------------------------------------------------------
// Stage 2+3 fused: per-batch producer/consumer via device-scope counter.
//   gram phase (chunk r): G[b][dd][d] += SCALE * sum_k cr[dd][k]*cp[d][k]
//   -> fetch_add(RELEASE) Cnt[b]; spin-acquire until Cnt[b]==48
//   xm phase (m0 = r*64): U[b][m][dd] = sum_d xT[m][d]*G[dd][d]  (U aliases cp;
//   safe: all batch-b cp readers released before any batch-b U write).
// Deadlock-safe by capacity: 384 blocks, 35.8 KB LDS -> 4 blocks/CU -> 1024
// slots >= 384; waits are intra-batch only.
// ---------------------------------------------------------------------------
__global__ __launch_bounds__(256) void k_gx(
    const float* __restrict__ cross, u16* __restrict__ cpU,
    const float* __restrict__ x, float* __restrict__ G,
    unsigned int* __restrict__ Cnt)
{
    __shared__ __align__(16) u16 As[64 * LDP];
    __shared__ __align__(16) u16 Bs[64 * LDP];
    __shared__ __align__(16) float T[64][68];
    const int r = blockIdx.x;      // 0..47: gram k-chunk AND xm m-tile
    const int b = blockIdx.y;
    const int t = threadIdx.x;
    const int lane = t & 63, wave = t >> 6;
    const int q = lane >> 4, tx = lane & 15;
    const int wm = (wave & 1) * 32, wn = (wave >> 1) * 32;
    float* Gb = G + b * 4096;

    // ---- gram phase ----
    {
        const int kb = r * 64;
        const float* crb = cross + b * BCN;
        const u16* cpb = cpU + b * BCN;
        f32x4 acc[2][2] = {};
        {
            const int rr = t >> 2, cq = t & 3;
            const float* src = crb + rr * K3 + kb;
            u16* dst = As + rr * LDP;
            #pragma unroll
            for (int u = 0; u < 4; ++u) {
                const int cl = (cq + 4 * u) * 4;
                float4 v = *reinterpret_cast<const float4*>(src + cl);
                ushort4 w; w.x = f2b(v.x); w.y = f2b(v.y); w.z = f2b(v.z); w.w = f2b(v.w);
                *reinterpret_cast<ushort4*>(dst + cl) = w;
            }
        }
        {
            const int rr = t >> 3, ch = (t & 7) * 8;
            *reinterpret_cast<uint4*>(Bs + rr * LDP + ch) =
                *reinterpret_cast<const uint4*>(cpb + rr * K3 + kb + ch);
            *reinterpret_cast<uint4*>(Bs + (rr + 32) * LDP + ch) =
                *reinterpret_cast<const uint4*>(cpb + (rr + 32) * K3 + kb + ch);
        }
        __syncthreads();
        MFMA8(As, Bs, acc)
        #pragma unroll
        for (int i = 0; i < 2; ++i)
            #pragma unroll
            for (int j = 0; j < 2; ++j)
                #pragma unroll
                for (int rr = 0; rr < 4; ++rr) {
                    const int dd = wm + i * 16 + q * 4 + rr;
                    const int d  = wn + j * 16 + tx;
                    atomicAdd(Gb + dd * DD + d, acc[i][j][rr] * SCALE);
                }
    }

    // ---- release / spin-acquire (per-batch) ----
    __syncthreads();                 // all this block's atomics issued
    if (t == 0) {
        __hip_atomic_fetch_add(&Cnt[b], 1u, __ATOMIC_RELEASE, __HIP_MEMORY_SCOPE_AGENT);
        while (__hip_atomic_load(&Cnt[b], __ATOMIC_ACQUIRE, __HIP_MEMORY_SCOPE_AGENT) < 48u)
            __builtin_amdgcn_s_sleep(8);
    }
    __syncthreads();                 // G[b] complete + acquire-fenced

    // ---- xm phase ----
    {
        const int m0 = r * 64;
        const int h   = m0 >> 8;
        const int nn0 = m0 & 255;
        const float* xb = x + b * BCN;
        f32x4 acc[2][2] = {};
        {   // T[d][nl] = x[(d*12+h)*256 + nn0+nl]  (coalesced rows)
            const int d = t >> 2, fq = t & 3;
            const float* src = xb + (d * HH + h) * NN + nn0;
            #pragma unroll
            for (int u = 0; u < 4; ++u) {
                const int nl = (fq + 4 * u) * 4;
                float4 v = *reinterpret_cast<const float4*>(src + nl);
                T[d][nl + 0] = v.x; T[d][nl + 1] = v.y; T[d][nl + 2] = v.z; T[d][nl + 3] = v.w;
            }
        }
        {   // Bs[dd][d] = cvt(G[dd][d])
            const int rr = t >> 2, cq = t & 3;
            const float* src = Gb + rr * DD;
            u16* dst = Bs + rr * LDP;
            #pragma unroll
            for (int u = 0; u < 4; ++u) {
                const int cl = (cq + 4 * u) * 4;
                float4 v = *reinterpret_cast<const float4*>(src + cl);
                ushort4 w; w.x = f2b(v.x); w.y = f2b(v.y); w.z = f2b(v.z); w.w = f2b(v.w);
                *reinterpret_cast<ushort4*>(dst + cl) = w;
            }
        }
        __syncthreads();
        {   // As[m_local][d] = cvt(T[d][m_local])  (transpose)
            const int nn = t >> 2, dq = t & 3;
            u16* dst = As + nn * LDP;
            #pragma unroll
            for (int u = 0; u < 4; ++u) {
                const int d4 = (dq + 4 * u) * 4;
                ushort4 w;
                w.x = f2b(T[d4 + 0][nn]); w.y = f2b(T[d4 + 1][nn]);
                w.z = f2b(T[d4 + 2][nn]); w.w = f2b(T[d4 + 3][nn]);
                *reinterpret_cast<ushort4*>(dst + d4) = w;
            }
        }
        __syncthreads();
        MFMA8(As, Bs, acc)
        u16* Ub = cpU + b * BCN;     // U aliases cp (safe post-release)
        #pragma unroll
        for (int i = 0; i < 2; ++i)
            #pragma unroll
            for (int j = 0; j < 2; ++j)
                #pragma unroll
                for (int rr = 0; rr < 4; ++rr) {
                    const int m  = m0 + wm + i * 16 + q * 4 + rr;
                    const int dd = wn + j * 16 + tx;
                    Ub[m * DD + dd] = f2b(acc[i][j][rr]);
                }
    }
}

// ---------------------------------------------------------------------------
// Stage 4: out[b,o,n] = x[b,o,n] + bd[o] + sum_k Wd[o,k]*U2[n,k]
// R4-proven version (1-deep register prefetch, single-buffer, 2 barriers/iter).
// ---------------------------------------------------------------------------
__global__ __launch_bounds__(256) void k_dep(
    const float* __restrict__ Wd, const u16* __restrict__ U,
    const float* __restrict__ bd, const float* __restrict__ x, float* __restrict__ out)
{
    __shared__ __align__(16) u16 As[64 * LDP];
    __shared__ __align__(16) u16 Bs[64 * LDP];
    const int n0 = blockIdx.x * 64;
    const int o0 = blockIdx.y * 64;
    const int b  = blockIdx.z;
    const int t = threadIdx.x;
    const int lane = t & 63, wave = t >> 6;
    const int q = lane >> 4, tx = lane & 15;
    const int wm = (wave & 1) * 32, wn = (wave >> 1) * 32;
    const int r4 = t >> 2, cq = t & 3;
    const int r8 = t >> 3, ch = (t & 7) * 8;
    const u16* Ub = U + b * BCN;
    const float* srcA0 = Wd + (o0 + r4) * CC;

    float4 ra[4]; uint4 rb[2];
    #pragma unroll
    for (int u = 0; u < 4; ++u)                 // prologue: iter-0 tiles -> regs
        ra[u] = *reinterpret_cast<const float4*>(srcA0 + (cq + 4 * u) * 4);
    rb[0] = *reinterpret_cast<const uint4*>(Ub + (n0 + r8) * CC + ch);
    rb[1] = *reinterpret_cast<const uint4*>(Ub + (n0 + r8 + 32) * CC + ch);

    f32x4 acc[2][2] = {};
    for (int it = 0; it < 12; ++it) {
        if (it > 0) __syncthreads();            // prev MFMA readers of As/Bs done
        {   // regs -> LDS
            u16* dst = As + r4 * LDP;
            #pragma unroll
            for (int u = 0; u < 4; ++u) {
                const int cl = (cq + 4 * u) * 4;
                ushort4 w; w.x = f2b(ra[u].x); w.y = f2b(ra[u].y);
                w.z = f2b(ra[u].z); w.w = f2b(ra[u].w);
                *reinterpret_cast<ushort4*>(dst + cl) = w;
            }
            *reinterpret_cast<uint4*>(Bs + r8 * LDP + ch) = rb[0];
            *reinterpret_cast<uint4*>(Bs + (r8 + 32) * LDP + ch) = rb[1];
        }
        if (it < 11) {   // issue next-iter loads; in flight across sync+MFMA
            const int c0 = (it + 1) * 64;
            #pragma unroll
            for (int u = 0; u < 4; ++u)
                ra[u] = *reinterpret_cast<const float4*>(srcA0 + c0 + (cq + 4 * u) * 4);
            rb[0] = *reinterpret_cast<const uint4*>(Ub + (n0 + r8) * CC + c0 + ch);
            rb[1] = *reinterpret_cast<const uint4*>(Ub + (n0 + r8 + 32) * CC + c0 + ch);
        }
        __syncthreads();
        MFMA8(As, Bs, acc)
    }
    #pragma unroll
    for (int i = 0; i < 2; ++i)
        #pragma unroll
        for (int j = 0; j < 2; ++j)
            #pragma unroll
            for (int r = 0; r < 4; ++r) {
                const int o = o0 + wm + i * 16 + q * 4 + r;
                const int n = n0 + wn + j * 16 + tx;
                const int idx = b * BCN + o * NN + n;
                out[idx] = acc[i][j][r] + bd[o] + x[idx];
            }
}

extern "C" void kernel_launch(void* const* d_in, const int* in_sizes, int n_in,
                              void* d_out, int out_size, void* d_ws, size_t ws_size,
                              hipStream_t stream) {
    const float* x_ori = (const float*)d_in[0];
    const float* cross = (const float*)d_in[1];
    const float* Wp    = (const float*)d_in[2];
    const float* bp    = (const float*)d_in[3];
    const float* Wd    = (const float*)d_in[4];
    const float* bd    = (const float*)d_in[5];
    float* out = (float*)d_out;

    // ws: [0, 3,145,728): cp bf16 [8][768][256]; ALIASED by U bf16 [8][3072][64]
    //     (cp dead after k_gx's gram phase; handoff fenced in-kernel).
    //     [3,145,728, +131,072): G f32 [8][64][64] (zeroed by k_proj blocks).
    //     [3,276,800, +32):      Cnt u32 [8]       (zeroed by k_proj blocks).
    u16*   cp = (u16*)d_ws;
    float* G  = (float*)((char*)d_ws + (size_t)BB * BCN * sizeof(u16));
    unsigned int* Cnt = (unsigned int*)((char*)d_ws + (size_t)BB * BCN * sizeof(u16)
                                        + (size_t)BB * DD * DD * sizeof(float));

    k_proj<<<dim3(4, 12, BB), 256, 0, stream>>>(Wp, cross, bp, cp, G, Cnt);
    k_gx  <<<dim3(48, BB), 256, 0, stream>>>(cross, cp, x_ori, G, Cnt);
    k_dep <<<dim3(4, 12, BB), 256, 0, stream>>>(Wd, cp, bd, x_ori, out);
}

// Round 8
// 118.657 us; speedup vs baseline: 1.1265x; 1.1265x over previous
//
#include <hip/hip_runtime.h>

typedef unsigned short u16;
typedef short bf16x8 __attribute__((ext_vector_type(8)));
typedef float f32x4 __attribute__((ext_vector_type(4)));

#define BB 8
#define CC 768
#define NN 256
#define HH 12
#define DD 64
#define K3 3072          // H*N
#define BCN 196608       // C*N per batch
#define SCALE 0.125f
#define LDP 72           // LDS pitch (u16): 144B rows, 16B-aligned, 2-way banks only

__device__ __forceinline__ u16 f2b(float f) {
    union { float f; unsigned int i; } v; v.f = f;
    unsigned int r = v.i + 0x7FFFu + ((v.i >> 16) & 1u);
    return (u16)(r >> 16);
}

// one 64x64x64 MFMA macro-step (4 waves, each 32x32, K=64 in two k-halves)
#define MFMA8(ASP, BSP, ACC)                                                              \
    _Pragma("unroll")                                                                     \
    for (int kk = 0; kk < 2; ++kk) {                                                      \
        bf16x8 a0 = *reinterpret_cast<bf16x8*>((ASP) + (wm + tx) * LDP + kk * 32 + q * 8);\
        bf16x8 a1 = *reinterpret_cast<bf16x8*>((ASP) + (wm + 16 + tx) * LDP + kk * 32 + q * 8);\
        bf16x8 b0 = *reinterpret_cast<bf16x8*>((BSP) + (wn + tx) * LDP + kk * 32 + q * 8);\
        bf16x8 b1 = *reinterpret_cast<bf16x8*>((BSP) + (wn + 16 + tx) * LDP + kk * 32 + q * 8);\
        ACC[0][0] = __builtin_amdgcn_mfma_f32_16x16x32_bf16(a0, b0, ACC[0][0], 0, 0, 0);  \
        ACC[0][1] = __builtin_amdgcn_mfma_f32_16x16x32_bf16(a0, b1, ACC[0][1], 0, 0, 0);  \
        ACC[1][0] = __builtin_amdgcn_mfma_f32_16x16x32_bf16(a1, b0, ACC[1][0], 0, 0, 0);  \
        ACC[1][1] = __builtin_amdgcn_mfma_f32_16x16x32_bf16(a1, b1, ACC[1][1], 0, 0, 0);  \
    }

// ---------------------------------------------------------------------------
// Stage 1: cp[b,o,n] = sum_c Wp[o,c]*cross[b,c,n] + bp[o]     (bf16 out)
// NT-MFMA 64x64x64 tiles, 12 K-iters with 1-deep register prefetch: iter k+1's
// global loads are issued right after iter k's regs->LDS writes, so HBM/L2
// latency hides under the transpose + MFMA phases. Blocks (0,0,b) zero G[b]
// (consumed by k_gram next dispatch — stream-ordered).
// ---------------------------------------------------------------------------
__global__ __launch_bounds__(256) void k_proj(
    const float* __restrict__ Wp, const float* __restrict__ cross,
    const float* __restrict__ bp, u16* __restrict__ cp, float* __restrict__ G)
{
    __shared__ __align__(16) u16 As[64 * LDP];
    __shared__ __align__(16) u16 Bs[64 * LDP];
    __shared__ __align__(16) float T[64][68];
    const int n0 = blockIdx.x * 64;
    const int o0 = blockIdx.y * 64;
    const int b  = blockIdx.z;
    const int t = threadIdx.x;
    const int lane = t & 63, wave = t >> 6;
    const int q = lane >> 4, tx = lane & 15;
    const int wm = (wave & 1) * 32, wn = (wave >> 1) * 32;
    const int r4 = t >> 2, cq = t & 3;

    if (blockIdx.x == 0 && blockIdx.y == 0) {   // zero G[b]
        float4 z = {0.f, 0.f, 0.f, 0.f};
        float* Gb = G + b * 4096;
        #pragma unroll
        for (int j = 0; j < 4; ++j)
            *reinterpret_cast<float4*>(Gb + t * 4 + j * 1024) = z;
    }

    const float* crb = cross + b * BCN;
    const float* wsrc = Wp + (o0 + r4) * CC;    // contiguous row o0+r4

    f32x4 acc[2][2] = {};
    float4 ra[4], rc[4];
    #pragma unroll
    for (int u = 0; u < 4; ++u) {               // prologue: iter-0 tiles -> regs
        const int cl = (cq + 4 * u) * 4;
        ra[u] = *reinterpret_cast<const float4*>(wsrc + cl);
        rc[u] = *reinterpret_cast<const float4*>(crb + r4 * NN + n0 + cl);
    }
    for (int it = 0; it < 12; ++it) {
        if (it > 0) __syncthreads();            // prev MFMA readers of As/Bs done
        {   // regs -> As (cvt) and T (f32)
            u16* dstA = As + r4 * LDP;
            #pragma unroll
            for (int u = 0; u < 4; ++u) {
                const int cl = (cq + 4 * u) * 4;
                ushort4 w; w.x = f2b(ra[u].x); w.y = f2b(ra[u].y);
                w.z = f2b(ra[u].z); w.w = f2b(ra[u].w);
                *reinterpret_cast<ushort4*>(dstA + cl) = w;
                T[r4][cl + 0] = rc[u].x; T[r4][cl + 1] = rc[u].y;
                T[r4][cl + 2] = rc[u].z; T[r4][cl + 3] = rc[u].w;
            }
        }
        if (it < 11) {   // issue next-iter loads; in flight across transpose+MFMA
            const int c0 = (it + 1) * 64;
            #pragma unroll
            for (int u = 0; u < 4; ++u) {
                const int cl = (cq + 4 * u) * 4;
                ra[u] = *reinterpret_cast<const float4*>(wsrc + c0 + cl);
                rc[u] = *reinterpret_cast<const float4*>(crb + (c0 + r4) * NN + n0 + cl);
            }
        }
        __syncthreads();
        {   // Bs[n][c] = cvt(T[c][n])  (transpose; T col reads are 2-way = free)
            const int nn = t >> 2, dq = t & 3;
            u16* dst = Bs + nn * LDP;
            #pragma unroll
            for (int u = 0; u < 4; ++u) {
                const int c4 = (dq + 4 * u) * 4;
                ushort4 w;
                w.x = f2b(T[c4 + 0][nn]); w.y = f2b(T[c4 + 1][nn]);
                w.z = f2b(T[c4 + 2][nn]); w.w = f2b(T[c4 + 3][nn]);
                *reinterpret_cast<ushort4*>(dst + c4) = w;
            }
        }
        __syncthreads();
        MFMA8(As, Bs, acc)
    }
    u16* cpb = cp + b * BCN;
    #pragma unroll
    for (int i = 0; i < 2; ++i)
        #pragma unroll
        for (int j = 0; j < 2; ++j)
            #pragma unroll
            for (int r = 0; r < 4; ++r) {
                const int o = o0 + wm + i * 16 + q * 4 + r;
                const int n = n0 + wn + j * 16 + tx;
                cpb[o * NN + n] = f2b(acc[i][j][r] + bp[o]);
            }
}

// ---------------------------------------------------------------------------
// Stage 2: G[b][dd][d] += SCALE * sum_k cross_view[dd][k]*cp_view[d][k]
// Split-K 48 x 64 chunks, f32 atomics (G pre-zeroed by k_proj).
// ---------------------------------------------------------------------------
__global__ __launch_bounds__(256) void k_gram(
    const float* __restrict__ cross, const u16* __restrict__ cp, float* __restrict__ G)
{
    __shared__ __align__(16) u16 As[64 * LDP];
    __shared__ __align__(16) u16 Bs[64 * LDP];
    const int kb = blockIdx.x * 64;
    const int b  = blockIdx.y;
    const int t = threadIdx.x;
    const int lane = t & 63, wave = t >> 6;
    const int q = lane >> 4, tx = lane & 15;
    const int wm = (wave & 1) * 32, wn = (wave >> 1) * 32;
    const float* crb = cross + b * BCN;
    const u16* cpb = cp + b * BCN;
    f32x4 acc[2][2] = {};
    {
        const int r = t >> 2, cq = t & 3;
        const float* src = crb + r * K3 + kb;
        u16* dst = As + r * LDP;
        #pragma unroll
        for (int u = 0; u < 4; ++u) {
            const int cl = (cq + 4 * u) * 4;
            float4 v = *reinterpret_cast<const float4*>(src + cl);
            ushort4 w; w.x = f2b(v.x); w.y = f2b(v.y); w.z = f2b(v.z); w.w = f2b(v.w);
            *reinterpret_cast<ushort4*>(dst + cl) = w;
        }
    }
    {
        const int r = t >> 3, ch = (t & 7) * 8;
        *reinterpret_cast<uint4*>(Bs + r * LDP + ch) =
            *reinterpret_cast<const uint4*>(cpb + r * K3 + kb + ch);
        *reinterpret_cast<uint4*>(Bs + (r + 32) * LDP + ch) =
            *reinterpret_cast<const uint4*>(cpb + (r + 32) * K3 + kb + ch);
    }
    __syncthreads();
    MFMA8(As, Bs, acc)
    float* Gb = G + b * 4096;
    #pragma unroll
    for (int i = 0; i < 2; ++i)
        #pragma unroll
        for (int j = 0; j < 2; ++j)
            #pragma unroll
            for (int r = 0; r < 4; ++r) {
                const int dd = wm + i * 16 + q * 4 + r;
                const int d  = wn + j * 16 + tx;
                atomicAdd(Gb + dd * DD + d, acc[i][j][r] * SCALE);
            }
}

// ---------------------------------------------------------------------------
// Stage 3: U[b][m][dd] = sum_d xT[m][d]*G[dd][d].  A-tile (x^T) built
// in-kernel via LDS f32 tile T. U (bf16) aliases cp. 48 m-tiles x 8 batches.
// ---------------------------------------------------------------------------
__global__ __launch_bounds__(256) void k_xm(
    const float* __restrict__ x, const float* __restrict__ G, u16* __restrict__ U)
{
    __shared__ __align__(16) u16 As[64 * LDP];
    __shared__ __align__(16) u16 Bs[64 * LDP];
    __shared__ __align__(16) float T[64][68];
    const int m0 = blockIdx.x * 64;
    const int b  = blockIdx.y;
    const int h   = m0 >> 8;       // head index (m = h*256 + nn)
    const int nn0 = m0 & 255;
    const int t = threadIdx.x;
    const int lane = t & 63, wave = t >> 6;
    const int q = lane >> 4, tx = lane & 15;
    const int wm = (wave & 1) * 32, wn = (wave >> 1) * 32;
    const float* xb = x + b * BCN;
    const float* Gb = G + b * 4096;
    f32x4 acc[2][2] = {};
    {   // T[d][nl] = x[(d*12+h)*256 + nn0+nl]  (coalesced rows)
        const int d = t >> 2, fq = t & 3;
        const float* src = xb + (d * HH + h) * NN + nn0;
        #pragma unroll
        for (int u = 0; u < 4; ++u) {
            const int nl = (fq + 4 * u) * 4;
            float4 v = *reinterpret_cast<const float4*>(src + nl);
            T[d][nl + 0] = v.x; T[d][nl + 1] = v.y; T[d][nl + 2] = v.z; T[d][nl + 3] = v.w;
        }
    }
    {   // Bs[dd][d] = cvt(G[dd][d])
        const int r = t >> 2, cq = t & 3;
        const float* src = Gb + r * DD;
        u16* dst = Bs + r * LDP;
        #pragma unroll
        for (int u = 0; u < 4; ++u) {
            const int cl = (cq + 4 * u) * 4;
            float4 v = *reinterpret_cast<const float4*>(src + cl);
            ushort4 w; w.x = f2b(v.x); w.y = f2b(v.y); w.z = f2b(v.z); w.w = f2b(v.w);
            *reinterpret_cast<ushort4*>(dst + cl) = w;
        }
    }
    __syncthreads();
    {   // As[m_local][d] = cvt(T[d][m_local])  (transpose)
        const int nn = t >> 2, dq = t & 3;
        u16* dst = As + nn * LDP;
        #pragma unroll
        for (int u = 0; u < 4; ++u) {
            const int d4 = (dq + 4 * u) * 4;
            ushort4 w;
            w.x = f2b(T[d4 + 0][nn]); w.y = f2b(T[d4 + 1][nn]);
            w.z = f2b(T[d4 + 2][nn]); w.w = f2b(T[d4 + 3][nn]);
            *reinterpret_cast<ushort4*>(dst + d4) = w;
        }
    }
    __syncthreads();
    MFMA8(As, Bs, acc)
    u16* Ub = U + b * BCN;
    #pragma unroll
    for (int i = 0; i < 2; ++i)
        #pragma unroll
        for (int j = 0; j < 2; ++j)
            #pragma unroll
            for (int r = 0; r < 4; ++r) {
                const int m  = m0 + wm + i * 16 + q * 4 + r;
                const int dd = wn + j * 16 + tx;
                Ub[m * DD + dd] = f2b(acc[i][j][r]);
            }
}

// ---------------------------------------------------------------------------
// Stage 4: out[b,o,n] = x[b,o,n] + bd[o] + sum_k Wd[o,k]*U2[n,k]
// A=Wd (f32 cvt), B=U2 = U flat viewed [256][768] (bf16, k-contig). Native NT.
// 12 K-iters with 1-deep register prefetch (loads of iter k+1 in flight
// across sync+MFMA of iter k).
// ---------------------------------------------------------------------------
__global__ __launch_bounds__(256) void k_dep(
    const float* __restrict__ Wd, const u16* __restrict__ U,
    const float* __restrict__ bd, const float* __restrict__ x, float* __restrict__ out)
{
    __shared__ __align__(16) u16 As[64 * LDP];
    __shared__ __align__(16) u16 Bs[64 * LDP];
    const int n0 = blockIdx.x * 64;
    const int o0 = blockIdx.y * 64;
    const int b  = blockIdx.z;
    const int t = threadIdx.x;
    const int lane = t & 63, wave = t >> 6;
    const int q = lane >> 4, tx = lane & 15;
    const int wm = (wave & 1) * 32, wn = (wave >> 1) * 32;
    const int r4 = t >> 2, cq = t & 3;
    const int r8 = t >> 3, ch = (t & 7) * 8;
    const u16* Ub = U + b * BCN;
    const float* srcA0 = Wd + (o0 + r4) * CC;

    float4 ra[4]; uint4 rb[2];
    #pragma unroll
    for (int u = 0; u < 4; ++u)                 // prologue: iter-0 tiles -> regs
        ra[u] = *reinterpret_cast<const float4*>(srcA0 + (cq + 4 * u) * 4);
    rb[0] = *reinterpret_cast<const uint4*>(Ub + (n0 + r8) * CC + ch);
    rb[1] = *reinterpret_cast<const uint4*>(Ub + (n0 + r8 + 32) * CC + ch);

    f32x4 acc[2][2] = {};
    for (int it = 0; it < 12; ++it) {
        if (it > 0) __syncthreads();            // prev MFMA readers of As/Bs done
        {   // regs -> LDS
            u16* dst = As + r4 * LDP;
            #pragma unroll
            for (int u = 0; u < 4; ++u) {
                const int cl = (cq + 4 * u) * 4;
                ushort4 w; w.x = f2b(ra[u].x); w.y = f2b(ra[u].y);
                w.z = f2b(ra[u].z); w.w = f2b(ra[u].w);
                *reinterpret_cast<ushort4*>(dst + cl) = w;
            }
            *reinterpret_cast<uint4*>(Bs + r8 * LDP + ch) = rb[0];
            *reinterpret_cast<uint4*>(Bs + (r8 + 32) * LDP + ch) = rb[1];
        }
        if (it < 11) {   // issue next-iter loads; in flight across sync+MFMA
            const int c0 = (it + 1) * 64;
            #pragma unroll
            for (int u = 0; u < 4; ++u)
                ra[u] = *reinterpret_cast<const float4*>(srcA0 + c0 + (cq + 4 * u) * 4);
            rb[0] = *reinterpret_cast<const uint4*>(Ub + (n0 + r8) * CC + c0 + ch);
            rb[1] = *reinterpret_cast<const uint4*>(Ub + (n0 + r8 + 32) * CC + c0 + ch);
        }
        __syncthreads();
        MFMA8(As, Bs, acc)
    }
    #pragma unroll
    for (int i = 0; i < 2; ++i)
        #pragma unroll
        for (int j = 0; j < 2; ++j)
            #pragma unroll
            for (int r = 0; r < 4; ++r) {
                const int o = o0 + wm + i * 16 + q * 4 + r;
                const int n = n0 + wn + j * 16 + tx;
                const int idx = b * BCN + o * NN + n;
                out[idx] = acc[i][j][r] + bd[o] + x[idx];
            }
}

extern "C" void kernel_launch(void* const* d_in, const int* in_sizes, int n_in,
                              void* d_out, int out_size, void* d_ws, size_t ws_size,
                              hipStream_t stream) {
    const float* x_ori = (const float*)d_in[0];
    const float* cross = (const float*)d_in[1];
    const float* Wp    = (const float*)d_in[2];
    const float* bp    = (const float*)d_in[3];
    const float* Wd    = (const float*)d_in[4];
    const float* bd    = (const float*)d_in[5];
    float* out = (float*)d_out;

    // ws: [0, 3,145,728): cp bf16 [8][768][256]; ALIASED by U bf16
    //     [8][3072][64] after k_gram (cp dead, stream-serialized).
    //     [3,145,728, +131,072): G f32 [8][64][64] (zeroed by k_proj blocks).
    u16*   cp = (u16*)d_ws;
    u16*   U  = (u16*)d_ws;
    float* G  = (float*)((char*)d_ws + (size_t)BB * BCN * sizeof(u16));

    k_proj<<<dim3(4, 12, BB), 256, 0, stream>>>(Wp, cross, bp, cp, G);
    k_gram<<<dim3(48, BB), 256, 0, stream>>>(cross, cp, G);
    k_xm  <<<dim3(48, BB), 256, 0, stream>>>(x_ori, G, U);
    k_dep <<<dim3(4, 12, BB), 256, 0, stream>>>(Wd, U, bd, x_ori, out);
}